// Round 1
// baseline (415.635 us; speedup 1.0000x reference)
//
#include <hip/hip_runtime.h>
#include <math.h>

#define BB 64
#define NN 8192
#define DD 128
#define CC 256
#define EPSF 1e-8f
#define ROWS 128   // rows of memory per block in head_dot

__device__ inline float softplusf(float x) {
    // matches jax.nn.softplus = logaddexp(x, 0)
    return fmaxf(x, 0.f) + log1pf(expf(-fabsf(x)));
}

// ---------------- kernel A: per-batch scalars + key ----------------
// grid = B, block = 128 (one thread per key element)
__global__ __launch_bounds__(128)
void head_small(const float* __restrict__ cs,
                const float* __restrict__ Wk,
                const float* __restrict__ Wb, const float* __restrict__ bb,
                const float* __restrict__ Wg, const float* __restrict__ bg,
                const float* __restrict__ Ws, const float* __restrict__ bs,
                const float* __restrict__ Wgam, const float* __restrict__ bgam,
                float* __restrict__ key_out, float* __restrict__ scal_out) {
    const int b = blockIdx.x;
    const int t = threadIdx.x;           // 0..127
    __shared__ float s_cs[CC];
    __shared__ float s_red[2];

    for (int c = t; c < CC; c += 128) s_cs[c] = cs[b * CC + c];
    __syncthreads();

    // key[d] = sum_c cs[c] * Wk[c*D + d]  (coalesced over d)
    float kacc = 0.f;
    #pragma unroll 8
    for (int c = 0; c < CC; ++c) kacc = fmaf(s_cs[c], Wk[c * DD + t], kacc);
    key_out[b * DD + t] = kacc;

    // 6 small dots, strided over c
    float a0 = 0.f, a1 = 0.f, a2 = 0.f, a3 = 0.f, a4 = 0.f, a5 = 0.f;
    for (int c = t; c < CC; c += 128) {
        float x = s_cs[c];
        a0 = fmaf(x, Wb[c], a0);
        a1 = fmaf(x, Wg[c], a1);
        a2 = fmaf(x, Ws[c * 3 + 0], a2);
        a3 = fmaf(x, Ws[c * 3 + 1], a3);
        a4 = fmaf(x, Ws[c * 3 + 2], a4);
        a5 = fmaf(x, Wgam[c], a5);
    }

    // block reduce (128 threads = 2 waves): pack 7 values sequentially
    float vals[7] = { kacc * kacc, a0, a1, a2, a3, a4, a5 };
    float outv[7];
    const int wid = t >> 6, lane = t & 63;
    for (int k = 0; k < 7; ++k) {
        float v = vals[k];
        for (int off = 32; off > 0; off >>= 1) v += __shfl_down(v, off);
        __syncthreads();
        if (lane == 0) s_red[wid] = v;
        __syncthreads();
        outv[k] = s_red[0] + s_red[1];
    }

    if (t == 0) {
        float key_norm = sqrtf(outv[0]);
        float beta  = softplusf(outv[1] + bb[0]) + 1.f;
        float gate  = 1.f / (1.f + expf(-(outv[2] + bg[0])));
        float sh0 = outv[3] + bs[0], sh1 = outv[4] + bs[1], sh2 = outv[5] + bs[2];
        float m = fmaxf(sh0, fmaxf(sh1, sh2));
        float e0 = expf(sh0 - m), e1 = expf(sh1 - m), e2 = expf(sh2 - m);
        float inv = 1.f / (e0 + e1 + e2);
        float gamma = softplusf(outv[6] + bgam[0]) + 1.f;
        float* s = scal_out + b * 8;
        s[0] = beta; s[1] = gate; s[2] = gamma;
        s[3] = e0 * inv; s[4] = e1 * inv; s[5] = e2 * inv;
        s[6] = key_norm; s[7] = 0.f;
    }
}

// ---------------- kernel B: the 256 MB streaming pass ----------------
// grid = (N/ROWS, B), block = 256. 8 groups of 32 lanes; each group reads one
// row (128 f32 = 32 float4, fully coalesced 512 B) per iteration, computes
// dot(key,row) and ||row||^2, shuffle-reduces, lane 0 writes beta*sim.
__global__ __launch_bounds__(256)
void head_dot(const float* __restrict__ mem,
              const float* __restrict__ key, const float* __restrict__ scal,
              float* __restrict__ out) {
    const int b = blockIdx.y;
    const int chunk = blockIdx.x * ROWS;
    const int t = threadIdx.x;
    const int g = t >> 5;      // group 0..7
    const int l = t & 31;      // lane-in-group

    const float4 k4 = ((const float4*)(key + b * DD))[l];
    const float beta = scal[b * 8 + 0];
    const float key_norm = scal[b * 8 + 6];
    const float* base = mem + (size_t)b * NN * DD;

    #pragma unroll 4
    for (int i = 0; i < ROWS / 8; ++i) {
        const int row = chunk + i * 8 + g;   // 8 consecutive rows per block-iter
        const float4 v = ((const float4*)(base + (size_t)row * DD))[l];
        float dot = v.x * k4.x + v.y * k4.y + v.z * k4.z + v.w * k4.w;
        float nr  = v.x * v.x + v.y * v.y + v.z * v.z + v.w * v.w;
        #pragma unroll
        for (int off = 16; off > 0; off >>= 1) {
            dot += __shfl_xor(dot, off, 32);
            nr  += __shfl_xor(nr,  off, 32);
        }
        if (l == 0) {
            float mem_norm = sqrtf(nr);
            float sim = dot / (key_norm * mem_norm + EPSF);
            out[(size_t)b * NN + row] = beta * sim;
        }
    }
}

// ---------------- block reduce helpers (1024 threads = 16 waves) ----------------
__device__ inline float blockReduceSum1024(float v, float* red) {
    for (int off = 32; off > 0; off >>= 1) v += __shfl_down(v, off);
    const int wid = threadIdx.x >> 6, lane = threadIdx.x & 63;
    __syncthreads();
    if (lane == 0) red[wid] = v;
    __syncthreads();
    if (wid == 0) {
        float r = (lane < 16) ? red[lane] : 0.f;
        for (int off = 8; off > 0; off >>= 1) r += __shfl_down(r, off);
        if (lane == 0) red[0] = r;
    }
    __syncthreads();
    return red[0];
}

__device__ inline float blockReduceMax1024(float v, float* red) {
    for (int off = 32; off > 0; off >>= 1) v = fmaxf(v, __shfl_down(v, off));
    const int wid = threadIdx.x >> 6, lane = threadIdx.x & 63;
    __syncthreads();
    if (lane == 0) red[wid] = v;
    __syncthreads();
    if (wid == 0) {
        float r = (lane < 16) ? red[lane] : -INFINITY;
        for (int off = 8; off > 0; off >>= 1) r = fmaxf(r, __shfl_down(r, off));
        if (lane == 0) red[0] = r;
    }
    __syncthreads();
    return red[0];
}

// ---------------- kernel C: softmax + gate + shift + sharpen ----------------
// grid = B, block = 1024. Whole per-batch row (8192 f32 = 32 KB) lives in LDS.
__global__ __launch_bounds__(1024)
void head_finish(const float* __restrict__ prev,
                 const float* __restrict__ scal, float* __restrict__ out) {
    const int b = blockIdx.x;
    const int t = threadIdx.x;
    __shared__ float w[NN];      // 32 KB
    __shared__ float red[16];

    const float gate  = scal[b * 8 + 1];
    const float gamma = scal[b * 8 + 2];
    const float s0 = scal[b * 8 + 3], s1 = scal[b * 8 + 4], s2 = scal[b * 8 + 5];

    // phase 1: load beta*sim, running max
    float lmax = -INFINITY;
    #pragma unroll
    for (int j = 0; j < NN / 1024; ++j) {
        const int i = t + j * 1024;
        const float v = out[(size_t)b * NN + i];
        w[i] = v;
        lmax = fmaxf(lmax, v);
    }
    const float gmax = blockReduceMax1024(lmax, red);

    // phase 2: exp + sum
    float lsum = 0.f;
    #pragma unroll
    for (int j = 0; j < NN / 1024; ++j) {
        const int i = t + j * 1024;
        const float e = expf(w[i] - gmax);
        w[i] = e;
        lsum += e;
    }
    const float gsum = blockReduceSum1024(lsum, red);
    const float invs = 1.f / gsum;

    // phase 3: gate * content + (1-gate) * prev
    #pragma unroll
    for (int j = 0; j < NN / 1024; ++j) {
        const int i = t + j * 1024;
        const float cw = w[i] * invs;
        w[i] = gate * cw + (1.f - gate) * prev[(size_t)b * NN + i];
    }
    __syncthreads();   // shift reads neighbors

    // phase 4: circular shift (offsets -1,0,+1) + sharpen
    // roll(w,-1)[i] = w[i+1]; roll(w,+1)[i] = w[i-1]
    float sharp[NN / 1024];
    float lps = 0.f;
    #pragma unroll
    for (int j = 0; j < NN / 1024; ++j) {
        const int i = t + j * 1024;
        const float sh = s0 * w[(i + 1) & (NN - 1)] + s1 * w[i] + s2 * w[(i - 1) & (NN - 1)];
        const float p = powf(sh + 1e-8f, gamma);
        sharp[j] = p;
        lps += p;
    }
    const float gps = blockReduceSum1024(lps, red);
    const float invp = 1.f / (gps + EPSF);

    #pragma unroll
    for (int j = 0; j < NN / 1024; ++j) {
        out[(size_t)b * NN + t + j * 1024] = sharp[j] * invp;
    }
}

extern "C" void kernel_launch(void* const* d_in, const int* in_sizes, int n_in,
                              void* d_out, int out_size, void* d_ws, size_t ws_size,
                              hipStream_t stream) {
    const float* mem  = (const float*)d_in[0];
    const float* cs   = (const float*)d_in[1];
    const float* prev = (const float*)d_in[2];
    const float* Wk   = (const float*)d_in[3];
    const float* Wb   = (const float*)d_in[4];
    const float* bb   = (const float*)d_in[5];
    const float* Wg   = (const float*)d_in[6];
    const float* bg   = (const float*)d_in[7];
    const float* Ws   = (const float*)d_in[8];
    const float* bs   = (const float*)d_in[9];
    const float* Wgam = (const float*)d_in[10];
    const float* bgam = (const float*)d_in[11];
    float* out = (float*)d_out;

    float* key  = (float*)d_ws;          // B*D floats = 32 KB
    float* scal = key + BB * DD;         // B*8 floats

    head_small<<<BB, 128, 0, stream>>>(cs, Wk, Wb, bb, Wg, bg, Ws, bs,
                                       Wgam, bgam, key, scal);
    dim3 gridB(NN / ROWS, BB);
    head_dot<<<gridB, 256, 0, stream>>>(mem, key, scal, out);
    head_finish<<<BB, 1024, 0, stream>>>(prev, scal, out);
}

// Round 2
// 407.456 us; speedup vs baseline: 1.0201x; 1.0201x over previous
//
#include <hip/hip_runtime.h>
#include <math.h>

#define BB 64
#define NN 8192
#define DD 128
#define CC 256
#define EPSF 1e-8f
#define ROWS 128   // rows of memory per block in head_dot

__device__ inline float softplusf(float x) {
    // matches jax.nn.softplus = logaddexp(x, 0)
    return fmaxf(x, 0.f) + log1pf(expf(-fabsf(x)));
}

// ---------------- kernel A: per-batch scalars + key ----------------
// grid = B, block = 128 (one thread per key element)
__global__ __launch_bounds__(128)
void head_small(const float* __restrict__ cs,
                const float* __restrict__ Wk,
                const float* __restrict__ Wb, const float* __restrict__ bb,
                const float* __restrict__ Wg, const float* __restrict__ bg,
                const float* __restrict__ Ws, const float* __restrict__ bs,
                const float* __restrict__ Wgam, const float* __restrict__ bgam,
                float* __restrict__ key_out, float* __restrict__ scal_out) {
    const int b = blockIdx.x;
    const int t = threadIdx.x;           // 0..127
    __shared__ float s_cs[CC];
    __shared__ float s_red[2];

    for (int c = t; c < CC; c += 128) s_cs[c] = cs[b * CC + c];
    __syncthreads();

    // key[d] = sum_c cs[c] * Wk[c*D + d]  (coalesced over d)
    float kacc = 0.f;
    #pragma unroll 16
    for (int c = 0; c < CC; ++c) kacc = fmaf(s_cs[c], Wk[c * DD + t], kacc);
    key_out[b * DD + t] = kacc;

    // 6 small dots, strided over c
    float a0 = 0.f, a1 = 0.f, a2 = 0.f, a3 = 0.f, a4 = 0.f, a5 = 0.f;
    for (int c = t; c < CC; c += 128) {
        float x = s_cs[c];
        a0 = fmaf(x, Wb[c], a0);
        a1 = fmaf(x, Wg[c], a1);
        a2 = fmaf(x, Ws[c * 3 + 0], a2);
        a3 = fmaf(x, Ws[c * 3 + 1], a3);
        a4 = fmaf(x, Ws[c * 3 + 2], a4);
        a5 = fmaf(x, Wgam[c], a5);
    }

    // block reduce (128 threads = 2 waves): pack 7 values sequentially
    float vals[7] = { kacc * kacc, a0, a1, a2, a3, a4, a5 };
    float outv[7];
    const int wid = t >> 6, lane = t & 63;
    for (int k = 0; k < 7; ++k) {
        float v = vals[k];
        for (int off = 32; off > 0; off >>= 1) v += __shfl_down(v, off);
        __syncthreads();
        if (lane == 0) s_red[wid] = v;
        __syncthreads();
        outv[k] = s_red[0] + s_red[1];
    }

    if (t == 0) {
        float key_norm = sqrtf(outv[0]);
        float beta  = softplusf(outv[1] + bb[0]) + 1.f;
        float gate  = 1.f / (1.f + expf(-(outv[2] + bg[0])));
        float sh0 = outv[3] + bs[0], sh1 = outv[4] + bs[1], sh2 = outv[5] + bs[2];
        float m = fmaxf(sh0, fmaxf(sh1, sh2));
        float e0 = expf(sh0 - m), e1 = expf(sh1 - m), e2 = expf(sh2 - m);
        float inv = 1.f / (e0 + e1 + e2);
        float gamma = softplusf(outv[6] + bgam[0]) + 1.f;
        float* s = scal_out + b * 8;
        s[0] = beta; s[1] = gate; s[2] = gamma;
        s[3] = e0 * inv; s[4] = e1 * inv; s[5] = e2 * inv;
        s[6] = key_norm; s[7] = 0.f;
    }
}

// ---------------- kernel B: the 256 MB streaming pass ----------------
// grid = (N/ROWS, B), block = 256 (4 waves). Each wave handles 4 rows per
// iteration: 16 lanes/row, each lane loads two float4s (256 B contiguous
// segments per instruction). 4-level butterfly reduce, results staged in LDS,
// one coalesced 512 B store per block.
__global__ __launch_bounds__(256)
void head_dot(const float* __restrict__ mem,
              const float* __restrict__ key, const float* __restrict__ scal,
              float* __restrict__ out) {
    const int b = blockIdx.y;
    const int chunk = blockIdx.x * ROWS;
    const int t = threadIdx.x;
    const int w = t >> 6;          // wave 0..3
    const int l = t & 63;
    const int sub = l >> 4;        // row-in-wave 0..3
    const int sl = l & 15;         // lane-in-row 0..15

    const float4 k0 = ((const float4*)(key + b * DD))[sl];
    const float4 k1 = ((const float4*)(key + b * DD))[sl + 16];
    const float beta = scal[b * 8 + 0];
    const float key_norm = scal[b * 8 + 6];
    const float* base = mem + (size_t)b * NN * DD;

    __shared__ float s_res[ROWS];

    #pragma unroll
    for (int i = 0; i < ROWS / 16; ++i) {      // 8 iterations
        const int row = chunk + i * 16 + w * 4 + sub;
        const float4* rp = (const float4*)(base + (size_t)row * DD);
        const float4 v0 = rp[sl];
        const float4 v1 = rp[sl + 16];
        float dot = v0.x * k0.x + v0.y * k0.y + v0.z * k0.z + v0.w * k0.w
                  + v1.x * k1.x + v1.y * k1.y + v1.z * k1.z + v1.w * k1.w;
        float nr  = v0.x * v0.x + v0.y * v0.y + v0.z * v0.z + v0.w * v0.w
                  + v1.x * v1.x + v1.y * v1.y + v1.z * v1.z + v1.w * v1.w;
        #pragma unroll
        for (int off = 8; off > 0; off >>= 1) {
            dot += __shfl_xor(dot, off);
            nr  += __shfl_xor(nr,  off);
        }
        if (sl == 0) {
            const float sim = dot / (key_norm * sqrtf(nr) + EPSF);
            s_res[i * 16 + w * 4 + sub] = beta * sim;
        }
    }
    __syncthreads();
    if (t < ROWS) out[(size_t)b * NN + chunk + t] = s_res[t];
}

// ---------------- block reduce helpers (1024 threads = 16 waves) ----------------
__device__ inline float blockReduceSum1024(float v, float* red) {
    for (int off = 32; off > 0; off >>= 1) v += __shfl_down(v, off);
    const int wid = threadIdx.x >> 6, lane = threadIdx.x & 63;
    __syncthreads();
    if (lane == 0) red[wid] = v;
    __syncthreads();
    if (wid == 0) {
        float r = (lane < 16) ? red[lane] : 0.f;
        for (int off = 8; off > 0; off >>= 1) r += __shfl_down(r, off);
        if (lane == 0) red[0] = r;
    }
    __syncthreads();
    return red[0];
}

__device__ inline float blockReduceMax1024(float v, float* red) {
    for (int off = 32; off > 0; off >>= 1) v = fmaxf(v, __shfl_down(v, off));
    const int wid = threadIdx.x >> 6, lane = threadIdx.x & 63;
    __syncthreads();
    if (lane == 0) red[wid] = v;
    __syncthreads();
    if (wid == 0) {
        float r = (lane < 16) ? red[lane] : -INFINITY;
        for (int off = 8; off > 0; off >>= 1) r = fmaxf(r, __shfl_down(r, off));
        if (lane == 0) red[0] = r;
    }
    __syncthreads();
    return red[0];
}

// ---------------- kernel C: softmax + gate + shift + sharpen ----------------
// grid = B, block = 1024. Whole per-batch row (8192 f32 = 32 KB) lives in LDS.
__global__ __launch_bounds__(1024)
void head_finish(const float* __restrict__ prev,
                 const float* __restrict__ scal, float* __restrict__ out) {
    const int b = blockIdx.x;
    const int t = threadIdx.x;
    __shared__ float w[NN];      // 32 KB
    __shared__ float red[16];

    const float gate  = scal[b * 8 + 1];
    const float gamma = scal[b * 8 + 2];
    const float s0 = scal[b * 8 + 3], s1 = scal[b * 8 + 4], s2 = scal[b * 8 + 5];

    const float4* out4  = (const float4*)(out  + (size_t)b * NN);
    const float4* prev4 = (const float4*)(prev + (size_t)b * NN);
    float4* w4 = (float4*)w;

    // phase 1: load beta*sim (float4), running max
    float lmax = -INFINITY;
    #pragma unroll
    for (int j = 0; j < NN / 4096; ++j) {         // 2 iterations of float4
        const int i4 = t + j * 1024;
        const float4 v = out4[i4];
        w4[i4] = v;
        lmax = fmaxf(lmax, fmaxf(fmaxf(v.x, v.y), fmaxf(v.z, v.w)));
    }
    const float gmax = blockReduceMax1024(lmax, red);

    // phase 2: exp + sum
    float lsum = 0.f;
    #pragma unroll
    for (int j = 0; j < NN / 1024; ++j) {
        const int i = t + j * 1024;
        const float e = expf(w[i] - gmax);
        w[i] = e;
        lsum += e;
    }
    const float gsum = blockReduceSum1024(lsum, red);
    const float invs = 1.f / gsum;

    // phase 3: gate * content + (1-gate) * prev
    #pragma unroll
    for (int j = 0; j < NN / 4096; ++j) {
        const int i4 = t + j * 1024;
        const float4 p = prev4[i4];
        float4 c = w4[i4];
        c.x = gate * c.x * invs + (1.f - gate) * p.x;
        c.y = gate * c.y * invs + (1.f - gate) * p.y;
        c.z = gate * c.z * invs + (1.f - gate) * p.z;
        c.w = gate * c.w * invs + (1.f - gate) * p.w;
        w4[i4] = c;
    }
    __syncthreads();   // shift reads neighbors

    // phase 4: circular shift (offsets -1,0,+1) + sharpen
    // roll(w,-1)[i] = w[i+1]; roll(w,+1)[i] = w[i-1]
    float sharp[NN / 1024];
    float lps = 0.f;
    #pragma unroll
    for (int j = 0; j < NN / 1024; ++j) {
        const int i = t + j * 1024;
        const float sh = s0 * w[(i + 1) & (NN - 1)] + s1 * w[i] + s2 * w[(i - 1) & (NN - 1)];
        const float p = powf(sh + 1e-8f, gamma);
        sharp[j] = p;
        lps += p;
    }
    const float gps = blockReduceSum1024(lps, red);
    const float invp = 1.f / (gps + EPSF);

    // final store (float4): sharp[j] holds elements t + j*1024; regroup via LDS
    __syncthreads();
    #pragma unroll
    for (int j = 0; j < NN / 1024; ++j) w[t + j * 1024] = sharp[j] * invp;
    __syncthreads();
    float4* o4 = (float4*)(out + (size_t)b * NN);
    #pragma unroll
    for (int j = 0; j < NN / 4096; ++j) {
        const int i4 = t + j * 1024;
        o4[i4] = w4[i4];
    }
}

extern "C" void kernel_launch(void* const* d_in, const int* in_sizes, int n_in,
                              void* d_out, int out_size, void* d_ws, size_t ws_size,
                              hipStream_t stream) {
    const float* mem  = (const float*)d_in[0];
    const float* cs   = (const float*)d_in[1];
    const float* prev = (const float*)d_in[2];
    const float* Wk   = (const float*)d_in[3];
    const float* Wb   = (const float*)d_in[4];
    const float* bb   = (const float*)d_in[5];
    const float* Wg   = (const float*)d_in[6];
    const float* bg   = (const float*)d_in[7];
    const float* Ws   = (const float*)d_in[8];
    const float* bs   = (const float*)d_in[9];
    const float* Wgam = (const float*)d_in[10];
    const float* bgam = (const float*)d_in[11];
    float* out = (float*)d_out;

    float* key  = (float*)d_ws;          // B*D floats = 32 KB
    float* scal = key + BB * DD;         // B*8 floats

    head_small<<<BB, 128, 0, stream>>>(cs, Wk, Wb, bb, Wg, bg, Ws, bs,
                                       Wgam, bgam, key, scal);
    dim3 gridB(NN / ROWS, BB);
    head_dot<<<gridB, 256, 0, stream>>>(mem, key, scal, out);
    head_finish<<<BB, 1024, 0, stream>>>(prev, scal, out);
}